// Round 1
// baseline (661.609 us; speedup 1.0000x reference)
//
#include <hip/hip_runtime.h>

// mute(x): m,e = frexp(x); if e > 1 return m else x.
// For finite normals: e > 1  <=>  biased exponent field >= 128 (|x| >= 2).
// frexp mantissa = same sign+mantissa bits, exponent field = 126 (value in [0.5,1)).
__device__ __forceinline__ float mute1(float v, unsigned on) {
    unsigned b = __float_as_uint(v);
    float m = __uint_as_float((b & 0x807FFFFFu) | 0x3F000000u);
    // exponent-field test without shift: (b & 0x7F800000) >= 0x40000000 <=> e >= 128
    return (on && ((b & 0x7F800000u) >= 0x40000000u)) ? m : v;
}

// true clang vector type so __builtin_nontemporal_{load,store} accepts it
typedef float f32x4 __attribute__((ext_vector_type(4)));

__device__ __forceinline__ f32x4 mute4(f32x4 v, unsigned sel) {
    v.x = mute1(v.x, sel & 1u);
    v.y = mute1(v.y, sel & 2u);
    v.z = mute1(v.z, sel & 4u);
    v.w = mute1(v.w, sel & 8u);
    return v;
}

// sel for float4 index q within the 28x28 image (196 float4s, 7 per row)
__device__ __forceinline__ unsigned sel_for(unsigned q, unsigned row_mask, unsigned col_mask) {
    unsigned h = q / 7u;                 // row
    unsigned w = (q - h * 7u) * 4u;      // base column of this float4
    return (((row_mask >> h) & 1u) ? 0xFu : 0u) | ((col_mask >> w) & 0xFu);
}

// Persistent grid-stride: 2048 blocks x 256 threads -> stride 524,288.
// n4 = 25,690,112 = 49 * 524,288, so each thread does exactly 7 batches of 7
// float4s; every load/store is wave-coalesced (lanes contiguous), 7 loads in
// flight per wave for latency hiding, nontemporal to keep the 822 MB stream
// out of L2/L3 (zero reuse).
__global__ __launch_bounds__(256, 4) void mute_kernel(
    const f32x4* __restrict__ x, f32x4* __restrict__ out,
    const int* __restrict__ rows, const int* __restrict__ cols, int n4)
{
    // rows/cols are kernel-arg-uniform with constant offsets -> scalar loads.
    unsigned row_mask = (1u << rows[0]) | (1u << rows[1]) | (1u << rows[2]) | (1u << rows[3]);
    unsigned col_mask = (1u << cols[0]) | (1u << cols[1]) | (1u << cols[2]) | (1u << cols[3]);

    const int stride = (int)(gridDim.x * 256u);
    int i = (int)(blockIdx.x * 256u + threadIdx.x);

    constexpr int U = 7;
    // fast path: full batches of U grid-stride elements
    for (; i + (U - 1) * stride < n4; i += U * stride) {
        f32x4 v[U];
        #pragma unroll
        for (int u = 0; u < U; ++u)
            v[u] = __builtin_nontemporal_load(&x[i + u * stride]);
        #pragma unroll
        for (int u = 0; u < U; ++u) {
            unsigned q = (unsigned)(i + u * stride) % 196u;   // magic-mul, ~4 VALU
            v[u] = mute4(v[u], sel_for(q, row_mask, col_mask));
        }
        #pragma unroll
        for (int u = 0; u < U; ++u)
            __builtin_nontemporal_store(v[u], &out[i + u * stride]);
    }
    // tail (not executed for the benchmark shape, kept for generality)
    for (; i < n4; i += stride) {
        unsigned q = (unsigned)i % 196u;
        __builtin_nontemporal_store(
            mute4(__builtin_nontemporal_load(&x[i]), sel_for(q, row_mask, col_mask)),
            &out[i]);
    }
}

extern "C" void kernel_launch(void* const* d_in, const int* in_sizes, int n_in,
                              void* d_out, int out_size, void* d_ws, size_t ws_size,
                              hipStream_t stream) {
    const float* x   = (const float*)d_in[0];
    const int* rows  = (const int*)d_in[1];
    const int* cols  = (const int*)d_in[2];
    float* out       = (float*)d_out;

    int n  = in_sizes[0];          // 131072*28*28 = 102,760,448 elements (div by 4)
    int n4 = n / 4;                // 25,690,112 = 49 * 524,288

    int blocks = 2048;             // 8 blocks/CU on 256 CUs; persistent grid-stride
    int max_needed = (n4 + 255) / 256;
    if (blocks > max_needed) blocks = max_needed;

    mute_kernel<<<blocks, 256, 0, stream>>>(
        (const f32x4*)x, (f32x4*)out, rows, cols, n4);
}

// Round 2
// 647.662 us; speedup vs baseline: 1.0215x; 1.0215x over previous
//
#include <hip/hip_runtime.h>

// mute(x): m,e = frexp(x); if e > 1 return m else x.
// For finite normals: e > 1  <=>  biased exponent field >= 128 (|x| >= 2).
// frexp mantissa = same sign+mantissa bits, exponent field = 126 (value in [0.5,1)).
__device__ __forceinline__ float mute1(float v, unsigned on) {
    unsigned b = __float_as_uint(v);
    float m = __uint_as_float((b & 0x807FFFFFu) | 0x3F000000u);
    return (on && ((b & 0x7F800000u) >= 0x40000000u)) ? m : v;
}

__device__ __forceinline__ float4 mute4(float4 v, unsigned sel) {
    v.x = mute1(v.x, sel & 1u);
    v.y = mute1(v.y, sel & 2u);
    v.z = mute1(v.z, sel & 4u);
    v.w = mute1(v.w, sel & 8u);
    return v;
}

// sel for float4 index q within the 28x28 image (196 float4s, 7 per row).
// bit j of sel = mute component j.
__device__ __forceinline__ unsigned sel_for(unsigned q, unsigned row_mask, unsigned col_mask) {
    unsigned h = q / 7u;                 // row
    unsigned w = (q - h * 7u) * 4u;      // base column of this float4
    return (((row_mask >> h) & 1u) ? 0xFu : 0u) | ((col_mask >> w) & 0xFu);
}

// Block-contiguous batching: each block owns a contiguous chunk of 256*U float4s
// (28 KB). Thread t handles chunk-local elements t, t+256, ..., t+(U-1)*256:
// every load/store is wave-coalesced (lanes contiguous), U loads in flight per
// wave grouped before U stores (latency hiding + DRAM bus turnaround), and the
// resident footprint stays compact -> high DRAM page-hit rate (the round-1
// 8 MB-stride grid-stride layout broke this and regressed 5%).
// n4 = 25,690,112 = 1792 * 14,336, so the benchmark shape has zero tail.
constexpr int U = 7;

__global__ __launch_bounds__(256) void mute_kernel(
    const float4* __restrict__ x, float4* __restrict__ out,
    const int* __restrict__ rows, const int* __restrict__ cols, int n4)
{
    // rows/cols are kernel-arg-uniform with constant offsets -> scalar loads.
    unsigned row_mask = (1u << rows[0]) | (1u << rows[1]) | (1u << rows[2]) | (1u << rows[3]);
    unsigned col_mask = (1u << cols[0]) | (1u << cols[1]) | (1u << cols[2]) | (1u << cols[3]);

    int base = (int)(blockIdx.x * (256u * U) + threadIdx.x);

    if (base + (U - 1) * 256 < n4) {
        // full block: all U elements in range
        float4 v[U];
        #pragma unroll
        for (int u = 0; u < U; ++u)
            v[u] = x[base + u * 256];
        #pragma unroll
        for (int u = 0; u < U; ++u) {
            unsigned q = (unsigned)(base + u * 256) % 196u;   // magic-mul
            v[u] = mute4(v[u], sel_for(q, row_mask, col_mask));
        }
        #pragma unroll
        for (int u = 0; u < U; ++u)
            out[base + u * 256] = v[u];
    } else {
        // tail block (not executed for the benchmark shape)
        for (int u = 0; u < U; ++u) {
            int i = base + u * 256;
            if (i < n4) {
                unsigned q = (unsigned)i % 196u;
                out[i] = mute4(x[i], sel_for(q, row_mask, col_mask));
            }
        }
    }
}

extern "C" void kernel_launch(void* const* d_in, const int* in_sizes, int n_in,
                              void* d_out, int out_size, void* d_ws, size_t ws_size,
                              hipStream_t stream) {
    const float* x   = (const float*)d_in[0];
    const int* rows  = (const int*)d_in[1];
    const int* cols  = (const int*)d_in[2];
    float* out       = (float*)d_out;

    int n  = in_sizes[0];          // 131072*28*28 = 102,760,448 elements (div by 4)
    int n4 = n / 4;                // 25,690,112 = 1792 * 14,336

    int chunk  = 256 * U;          // 1792 float4s = 28 KB per block
    int blocks = (n4 + chunk - 1) / chunk;   // 14,336 exactly for the bench shape

    mute_kernel<<<blocks, 256, 0, stream>>>(
        (const float4*)x, (float4*)out, rows, cols, n4);
}